// Round 7
// baseline (384.714 us; speedup 1.0000x reference)
//
#include <hip/hip_runtime.h>

#define B_      8
#define N_      8192
#define M_      2048
#define S_      32
#define C_FEAT  128
#define C_OUT   131   // 3 + 128

// Padded selection indices (b, m, s) — 2 MB. Fully rewritten by scan_kernel
// before feat_kernel reads it (pad guarantees every slot is written).
__device__ int g_idx[(size_t)B_ * M_ * S_];

typedef float f32x4_t __attribute__((ext_vector_type(4)));
__device__ __forceinline__ void store_nt(float* p, float4 v) {
    f32x4_t x; x.x = v.x; x.y = v.y; x.z = v.z; x.w = v.w;
    __builtin_nontemporal_store(x, (f32x4_t*)p);
}

// Scan: one 512-thread block per 8 consecutive m (same b); wave w owns query
// m0+w (the r2/r4-verified per-wave structure, GPB=1). Emits the 3 coord
// channels directly (verified 1 KB-run store pattern) + packed g_idx.
//
// !!! DISTANCE BLOCK IS BIT-EXACT vs THE numpy-f32 REFERENCE — DO NOT TOUCH !!!
//   qq, pp: forward sequential  ((x^2 + y^2) + z^2)      [np pairwise_sum n<8]
//   dot:    REVERSED sequential ((z*z' + y*y') + x*x')   [np einsum d=3
//           descending switch-fallthrough remainder, scalar mul+add, no FMA]
//   dist = fl32( fl32(qq+pp) - fl32(2*dot) );  mask = dist < f32(0.04) strict
// Selection order: ascending rounds x ascending lane = ascending n, identical
// prefix-popcount slotting + batch-granularity early exit as verified r0-r4.
__global__ __launch_bounds__(512) void scan_kernel(
    const float* __restrict__ xyz,
    const float* __restrict__ new_xyz,
    float* __restrict__ out)
{
    __shared__ float4 s_sel[8][S_];   // {px,py,pz,__int_as_float(n)} per slot
    __shared__ float  s_q[8][3];
    __shared__ int    s_done[8];

    // XCD pinning: batch b's blocks on XCD b (xyz scan + idx stay L2-local).
    unsigned i = blockIdx.x;
    unsigned b = i & 7u;
    unsigned m0 = (i >> 3) * 8u;
    unsigned t = threadIdx.x;
    unsigned w = t >> 6, lane = t & 63u;
    const float* P = xyz + (size_t)b * N_ * 3;

    // ---- per-wave ball-query scan (no block barriers) ----
    const float* q = new_xyz + ((size_t)(b * M_ + m0 + w)) * 3;
    float qx = q[0], qy = q[1], qz = q[2];
    if (lane == 0) { s_q[w][0] = qx; s_q[w][1] = qy; s_q[w][2] = qz; }
    float qq = __fadd_rn(__fadd_rn(__fmul_rn(qx,qx), __fmul_rn(qy,qy)), __fmul_rn(qz,qz));

    int done = 0;   // wave-uniform
    for (int nb = 0; nb < N_ && done < S_; nb += 256) {
        float px[4], py[4], pz[4];
        #pragma unroll
        for (int r = 0; r < 4; ++r) {      // all 12 loads issued up front
            int n = nb + r * 64 + (int)lane;
            px[r] = P[n*3+0]; py[r] = P[n*3+1]; pz[r] = P[n*3+2];
        }
        #pragma unroll
        for (int r = 0; r < 4; ++r) {
            float pp = __fadd_rn(__fadd_rn(__fmul_rn(px[r],px[r]), __fmul_rn(py[r],py[r])), __fmul_rn(pz[r],pz[r]));
            float dt = __fadd_rn(__fadd_rn(__fmul_rn(qz,pz[r]), __fmul_rn(qy,py[r])), __fmul_rn(qx,px[r]));
            float d  = __fsub_rn(__fadd_rn(qq, pp), __fmul_rn(2.0f, dt));
            unsigned long long mk = __ballot(d < 0.04f);   // strict <, f32(0.04)
            if ((mk >> lane) & 1ull) {
                int slot = done + __popcll(mk & ((1ull << lane) - 1ull));
                if (slot < S_) {
                    float4 v;
                    v.x = px[r]; v.y = py[r]; v.z = pz[r];
                    v.w = __int_as_float(nb + r * 64 + (int)lane);
                    s_sel[w][slot] = v;
                }
            }
            done += (int)__popcll(mk);
        }
    }
    if (lane == 0) s_done[w] = done;
    __syncthreads();

    // ---- Pad: slots [total,32) <- slot 0 if any valid, else {P[0..2], 0} ----
    if (t < 256) {
        int w2 = (int)(t >> 5), s = (int)(t & 31u);
        int dn = s_done[w2];
        int total = dn < S_ ? dn : S_;
        if (s >= total) {
            float4 v;
            if (dn > 0) v = s_sel[w2][0];   // slot 0 valid when dn>0
            else { v.x = P[0]; v.y = P[1]; v.z = P[2]; v.w = __int_as_float(0); }
            s_sel[w2][s] = v;
        }
    }
    __syncthreads();

    // ---- coord channels 0..2: 3 waves x 8 m x 32 s = 1 KB contiguous runs ----
    if (t < 192) {
        unsigned ch = t >> 6, l = t & 63u, qi = l >> 3, s4 = (l & 7u) * 4u;
        float qc = s_q[qi][ch];
        const float* sp = (const float*)&s_sel[qi][0];
        float4 v;
        v.x = __fsub_rn(sp[(s4 + 0) * 4 + ch], qc);
        v.y = __fsub_rn(sp[(s4 + 1) * 4 + ch], qc);
        v.z = __fsub_rn(sp[(s4 + 2) * 4 + ch], qc);
        v.w = __fsub_rn(sp[(s4 + 3) * 4 + ch], qc);
        size_t off = (((size_t)(b * C_OUT + ch)) * M_ + (m0 + qi)) * S_ + s4;
        store_nt(out + off, v);
    }

    // ---- idx dump: 8 q x 32 s ints = 1 KB contiguous, coalesced ----
    if (t < 256)
        g_idx[((size_t)(b * M_ + m0)) * S_ + t] = __float_as_int(s_sel[t >> 5][t & 31u].w);
}

// Feature gather: one 256-thread block per (b, ch). The 32 KB feature row's hot
// span (~low-n, ball-query early exit) is L2-resident on XCD b after first
// touch; each gather is a 4 B L2 read. Output slice for (b,ch) = contiguous
// 256 KB, NT float4 streamed. No transpose, no staging buffer, no LDS.
__global__ __launch_bounds__(256) void feat_kernel(
    const float* __restrict__ features,
    float* __restrict__ out)
{
    unsigned i = blockIdx.x;
    unsigned b = i & 7u;              // XCD pinning matches scan
    unsigned ch = i >> 3;             // 0..127
    const float* frow = features + ((size_t)(b * C_FEAT + ch)) * N_;
    const int4*  idx  = (const int4*)(g_idx + (size_t)b * M_ * S_);
    float* orow = out + ((size_t)(b * C_OUT + 3 + ch)) * M_ * S_;

    #pragma unroll 4
    for (unsigned u = threadIdx.x; u < (M_ * S_) / 4; u += 256) {
        int4 gi = idx[u];             // 16 B coalesced, XCD-local L2
        float4 v;
        v.x = frow[gi.x];
        v.y = frow[gi.y];
        v.z = frow[gi.z];
        v.w = frow[gi.w];
        store_nt(orow + u * 4u, v);   // contiguous stream per (b,ch)
    }
}

extern "C" void kernel_launch(void* const* d_in, const int* in_sizes, int n_in,
                              void* d_out, int out_size, void* d_ws, size_t ws_size,
                              hipStream_t stream) {
    const float* xyz      = (const float*)d_in[0];  // (8,8192,3) f32
    const float* new_xyz  = (const float*)d_in[1];  // (8,2048,3) f32
    const float* features = (const float*)d_in[2];  // (8,128,8192) f32
    float* out = (float*)d_out;                     // (8,131,2048,32) f32

    scan_kernel<<<dim3(B_ * M_ / 8), dim3(512), 0, stream>>>(xyz, new_xyz, out);
    feat_kernel<<<dim3(B_ * C_FEAT), dim3(256), 0, stream>>>(features, out);
}

// Round 8
// 382.545 us; speedup vs baseline: 1.0057x; 1.0057x over previous
//
#include <hip/hip_runtime.h>

#define B_      8
#define N_      8192
#define M_      2048
#define S_      32
#define C_FEAT  128
#define C_OUT   131   // 3 + 128
#define G_      8     // queries (consecutive m) per block

// Transposed features (b, n, c), f32 — module-owned static device memory (33.5 MB).
__device__ float g_ft[(size_t)B_ * N_ * C_FEAT];

typedef float f32x4_t __attribute__((ext_vector_type(4)));
__device__ __forceinline__ void store_nt(float* p, float4 v) {
    f32x4_t x; x.x = v.x; x.y = v.y; x.z = v.z; x.w = v.w;
    __builtin_nontemporal_store(x, (f32x4_t*)p);
}

// Barrier that does NOT drain vmcnt: LDS deps are ordered by lgkmcnt(0); in-flight
// global loads (prefetch) and NT stores stay in flight across it. (r4-verified.)
__device__ __forceinline__ void lds_barrier() {
    asm volatile("s_waitcnt lgkmcnt(0)" ::: "memory");
    __builtin_amdgcn_s_barrier();
}

// features (B, C, N) -> g_ft (B, N, C). 64x64 f32 tile, float4 both sides.
// Grid linearized so b = blockIdx&7 (same XCD pinning as fused_kernel); n-tiles
// in reverse so hot low-n rows are most-recently-written in XCD b's L2.
__global__ __launch_bounds__(256) void transpose_kernel(
    const float* __restrict__ f)
{
    __shared__ float tile[64][68];
    unsigned x = blockIdx.x;
    int b = (int)(x & 7u);
    unsigned r = x >> 3;                      // 0..255 = (n-tile, c-tile)
    int c0 = (int)(r & 1u) * 64;
    int n0 = (127 - (int)(r >> 1)) * 64;      // reverse: low n written last
    int t = threadIdx.x;

    int nt = t & 15, cr0 = t >> 4;            // 16 float4 cols (64 n), 16 c-rows/pass
    #pragma unroll
    for (int pass = 0; pass < 4; ++pass) {
        int cr = cr0 + pass * 16;
        float4 v = *((const float4*)&f[((size_t)(b * C_FEAT + c0 + cr)) * N_ + n0 + nt * 4]);
        *((float4*)&tile[cr][nt * 4]) = v;    // byte pitch 272 = 17*16, 16B-aligned
    }
    __syncthreads();
    int ct = t & 15, nr0 = t >> 4;            // 16 float4 cols (64 c), 16 n-rows/pass
    #pragma unroll
    for (int pass = 0; pass < 4; ++pass) {
        int nr = nr0 + pass * 16;
        float4 v;
        v.x = tile[ct*4+0][nr];
        v.y = tile[ct*4+1][nr];
        v.z = tile[ct*4+2][nr];
        v.w = tile[ct*4+3][nr];
        *((float4*)&g_ft[((size_t)(b * N_ + n0 + nr)) * C_FEAT + c0 + ct * 4]) = v;
    }
}

// One 512-thread block per 8 consecutive m (same b). (r4-verified, verbatim.)
//
// !!! DISTANCE BLOCK IS BIT-EXACT vs THE numpy-f32 REFERENCE — DO NOT TOUCH !!!
//   qq, pp: forward sequential  ((x^2 + y^2) + z^2)      [np pairwise_sum n<8]
//   dot:    REVERSED sequential ((z*z' + y*y') + x*x')   [np einsum d=3
//           descending switch-fallthrough remainder, scalar mul+add, no FMA]
//   dist = fl32( fl32(qq+pp) - fl32(2*dot) );  mask = dist < f32(0.04) strict
// Selection order: ascending rounds x ascending lane = ascending n, identical
// prefix-popcount slotting + batch-granularity early exit as verified r0-r4.
__global__ __launch_bounds__(512, 4) void fused_kernel(
    const float* __restrict__ xyz,
    const float* __restrict__ new_xyz,
    float* __restrict__ out)
{
    __shared__ float4 s_sel[G_][S_];   // {px,py,pz,__int_as_float(n)} per slot
    __shared__ float  s_q[G_][3];
    __shared__ int    s_done[G_];
    __shared__ float  sT[32][256];     // [chunk-local channel][q*32+s]

    unsigned i = blockIdx.x;
    unsigned b = i & 7u;
    unsigned m0 = (i >> 3) * G_;
    unsigned t = threadIdx.x;
    unsigned w = t >> 6, lane = t & 63u;

    // ---- Phase 1: per-wave ball-query scan ----
    const float* q = new_xyz + ((size_t)(b * M_ + m0 + w)) * 3;
    float qx = q[0], qy = q[1], qz = q[2];
    if (lane == 0) { s_q[w][0] = qx; s_q[w][1] = qy; s_q[w][2] = qz; }
    float qq = __fadd_rn(__fadd_rn(__fmul_rn(qx,qx), __fmul_rn(qy,qy)), __fmul_rn(qz,qz));
    const float* P = xyz + (size_t)b * N_ * 3;

    int done = 0;   // wave-uniform
    for (int nb = 0; nb < N_ && done < S_; nb += 256) {
        float px[4], py[4], pz[4];
        #pragma unroll
        for (int r = 0; r < 4; ++r) {      // all 12 loads issued up front
            int n = nb + r * 64 + (int)lane;
            px[r] = P[n*3+0]; py[r] = P[n*3+1]; pz[r] = P[n*3+2];
        }
        #pragma unroll
        for (int r = 0; r < 4; ++r) {
            float pp = __fadd_rn(__fadd_rn(__fmul_rn(px[r],px[r]), __fmul_rn(py[r],py[r])), __fmul_rn(pz[r],pz[r]));
            float dt = __fadd_rn(__fadd_rn(__fmul_rn(qz,pz[r]), __fmul_rn(qy,py[r])), __fmul_rn(qx,px[r]));
            float d  = __fsub_rn(__fadd_rn(qq, pp), __fmul_rn(2.0f, dt));
            unsigned long long mk = __ballot(d < 0.04f);   // strict <, f32(0.04)
            if ((mk >> lane) & 1ull) {
                int slot = done + __popcll(mk & ((1ull << lane) - 1ull));
                if (slot < S_) {
                    float4 v;
                    v.x = px[r]; v.y = py[r]; v.z = pz[r];
                    v.w = __int_as_float(nb + r * 64 + (int)lane);
                    s_sel[w][slot] = v;
                }
            }
            done += (int)__popcll(mk);
        }
    }
    if (lane == 0) s_done[w] = done;
    __syncthreads();

    // ---- Pad: slots [total,32) <- slot 0 if any valid, else {P[0..2], 0} ----
    if (t < 256) {
        int w2 = (int)(t >> 5), s = (int)(t & 31u);
        int dn = s_done[w2];
        int total = dn < S_ ? dn : S_;
        if (s >= total) {
            float4 v;
            if (dn > 0) v = s_sel[w2][0];   // slot 0 valid when dn>0
            else { v.x = P[0]; v.y = P[1]; v.z = P[2]; v.w = __int_as_float(0); }
            s_sel[w2][s] = v;
        }
    }
    __syncthreads();

    // ---- Phase 2a: coord channels 0..2 (3 waves x 8 m x 32 s = 1 KB runs) ----
    if (t < 192) {
        unsigned ch = t >> 6, l = t & 63u, qi = l >> 3, s4 = (l & 7u) * 4u;
        float qc = s_q[qi][ch];
        const float* sp = (const float*)&s_sel[qi][0];
        float4 v;
        v.x = __fsub_rn(sp[(s4 + 0) * 4 + ch], qc);
        v.y = __fsub_rn(sp[(s4 + 1) * 4 + ch], qc);
        v.z = __fsub_rn(sp[(s4 + 2) * 4 + ch], qc);
        v.w = __fsub_rn(sp[(s4 + 3) * 4 + ch], qc);
        size_t off = (((size_t)(b * C_OUT + ch)) * M_ + (m0 + qi)) * S_ + s4;
        store_nt(out + off, v);
    }

    // ---- Phase 2b: feature channels, 4 chunks of 32, pipelined gather ----
    unsigned p = t >> 1, h = t & 1u;           // pair per (q,s); 64 B halves
    unsigned qg = p >> 5, sg = p & 31u;
    float4 selv = s_sel[qg][sg];               // b128 read, conflict-free
    int n = __float_as_int(selv.w);
    const float* grow = g_ft + ((size_t)(b * N_ + n)) * C_FEAT + h * 16u;

    float4 r0 = ((const float4*)grow)[0];
    float4 r1 = ((const float4*)grow)[1];
    float4 r2 = ((const float4*)grow)[2];
    float4 r3 = ((const float4*)grow)[3];

    for (int k = 0; k < 4; ++k) {
        float4 n0v, n1v, n2v, n3v;
        if (k < 3) {                           // prefetch chunk k+1 (T14)
            const float4* src = (const float4*)(grow + (k + 1) * 32);
            n0v = src[0]; n1v = src[1]; n2v = src[2]; n3v = src[3];
        }
        unsigned cb = h * 16u;
        // Scatter: lanes 2p,2p+1 share a bank (2-way aliasing = free).
        sT[cb +  0][p] = r0.x; sT[cb +  1][p] = r0.y; sT[cb +  2][p] = r0.z; sT[cb +  3][p] = r0.w;
        sT[cb +  4][p] = r1.x; sT[cb +  5][p] = r1.y; sT[cb +  6][p] = r1.z; sT[cb +  7][p] = r1.w;
        sT[cb +  8][p] = r2.x; sT[cb +  9][p] = r2.y; sT[cb + 10][p] = r2.z; sT[cb + 11][p] = r2.w;
        sT[cb + 12][p] = r3.x; sT[cb + 13][p] = r3.y; sT[cb + 14][p] = r3.z; sT[cb + 15][p] = r3.w;
        lds_barrier();                         // scatter visible; VMEM stays in flight
        #pragma unroll
        for (int rep = 0; rep < 4; ++rep) {
            unsigned idx = rep * 512u + t;     // 32 ch x 64 float4
            unsigned chl = idx >> 6;           // wave-uniform channel
            unsigned l4  = (idx & 63u) * 4u;   // float offset in the 1 KB run
            float4 v = *((const float4*)&sT[chl][l4]);   // contiguous b128
            size_t off = (((size_t)(b * C_OUT + 3 + k * 32 + chl)) * M_ + m0) * S_ + l4;
            store_nt(out + off, v);
        }
        if (k < 3) lds_barrier();              // protect sT before next scatter
        r0 = n0v; r1 = n1v; r2 = n2v; r3 = n3v;
    }
}

extern "C" void kernel_launch(void* const* d_in, const int* in_sizes, int n_in,
                              void* d_out, int out_size, void* d_ws, size_t ws_size,
                              hipStream_t stream) {
    const float* xyz      = (const float*)d_in[0];  // (8,8192,3) f32
    const float* new_xyz  = (const float*)d_in[1];  // (8,2048,3) f32
    const float* features = (const float*)d_in[2];  // (8,128,8192) f32
    float* out = (float*)d_out;                     // (8,131,2048,32) f32

    // ATTRIBUTION ROUND: fused launched TWICE (idempotent — rewrites identical
    // values). F = dur_this_round - 323.3 µs, valid under either fill-attribution
    // model. Revert to single launch next round.
    transpose_kernel<<<dim3((N_ / 64) * (C_FEAT / 64) * B_), dim3(256), 0, stream>>>(features);
    fused_kernel<<<dim3(B_ * M_ / G_), dim3(512), 0, stream>>>(xyz, new_xyz, out);
    fused_kernel<<<dim3(B_ * M_ / G_), dim3(512), 0, stream>>>(xyz, new_xyz, out);
}

// Round 9
// 331.640 us; speedup vs baseline: 1.1600x; 1.1535x over previous
//
#include <hip/hip_runtime.h>

#define B_      8
#define N_      8192
#define M_      2048
#define S_      32
#define C_FEAT  128
#define C_OUT   131   // 3 + 128
#define G_      8     // queries (consecutive m) per block

// Transposed features (b, n, c), f32 — module-owned static device memory (33.5 MB).
__device__ float g_ft[(size_t)B_ * N_ * C_FEAT];

typedef float f32x4_t __attribute__((ext_vector_type(4)));
__device__ __forceinline__ void store_nt(float* p, float4 v) {
    f32x4_t x; x.x = v.x; x.y = v.y; x.z = v.z; x.w = v.w;
    __builtin_nontemporal_store(x, (f32x4_t*)p);
}

// Barrier that does NOT drain vmcnt: LDS deps are ordered by lgkmcnt(0); in-flight
// global loads (prefetch) and NT stores stay in flight across it. (r4-verified.)
__device__ __forceinline__ void lds_barrier() {
    asm volatile("s_waitcnt lgkmcnt(0)" ::: "memory");
    __builtin_amdgcn_s_barrier();
}

// features (B, C, N) -> g_ft (B, N, C). 64x64 f32 tile, float4 both sides.
// Grid linearized so b = blockIdx&7 (same XCD pinning as fused_kernel); n-tiles
// in reverse so hot low-n rows are most-recently-written in XCD b's L2.
__global__ __launch_bounds__(256) void transpose_kernel(
    const float* __restrict__ f)
{
    __shared__ float tile[64][68];
    unsigned x = blockIdx.x;
    int b = (int)(x & 7u);
    unsigned r = x >> 3;                      // 0..255 = (n-tile, c-tile)
    int c0 = (int)(r & 1u) * 64;
    int n0 = (127 - (int)(r >> 1)) * 64;      // reverse: low n written last
    int t = threadIdx.x;

    int nt = t & 15, cr0 = t >> 4;            // 16 float4 cols (64 n), 16 c-rows/pass
    #pragma unroll
    for (int pass = 0; pass < 4; ++pass) {
        int cr = cr0 + pass * 16;
        float4 v = *((const float4*)&f[((size_t)(b * C_FEAT + c0 + cr)) * N_ + n0 + nt * 4]);
        *((float4*)&tile[cr][nt * 4]) = v;    // byte pitch 272 = 17*16, 16B-aligned
    }
    __syncthreads();
    int ct = t & 15, nr0 = t >> 4;            // 16 float4 cols (64 c), 16 n-rows/pass
    #pragma unroll
    for (int pass = 0; pass < 4; ++pass) {
        int nr = nr0 + pass * 16;
        float4 v;
        v.x = tile[ct*4+0][nr];
        v.y = tile[ct*4+1][nr];
        v.z = tile[ct*4+2][nr];
        v.w = tile[ct*4+3][nr];
        *((float4*)&g_ft[((size_t)(b * N_ + n0 + nr)) * C_FEAT + c0 + ct * 4]) = v;
    }
}

// One 512-thread block per 8 consecutive m (same b). (r4-verified, verbatim.)
//
// !!! DISTANCE BLOCK IS BIT-EXACT vs THE numpy-f32 REFERENCE — DO NOT TOUCH !!!
//   qq, pp: forward sequential  ((x^2 + y^2) + z^2)      [np pairwise_sum n<8]
//   dot:    REVERSED sequential ((z*z' + y*y') + x*x')   [np einsum d=3
//           descending switch-fallthrough remainder, scalar mul+add, no FMA]
//   dist = fl32( fl32(qq+pp) - fl32(2*dot) );  mask = dist < f32(0.04) strict
// Selection order: ascending rounds x ascending lane = ascending n, identical
// prefix-popcount slotting + batch-granularity early exit as verified r0-r4.
__global__ __launch_bounds__(512, 4) void fused_kernel(
    const float* __restrict__ xyz,
    const float* __restrict__ new_xyz,
    float* __restrict__ out)
{
    __shared__ float4 s_sel[G_][S_];   // {px,py,pz,__int_as_float(n)} per slot
    __shared__ float  s_q[G_][3];
    __shared__ int    s_done[G_];
    __shared__ float  sT[32][256];     // [chunk-local channel][q*32+s]

    unsigned i = blockIdx.x;
    unsigned b = i & 7u;
    unsigned m0 = (i >> 3) * G_;
    unsigned t = threadIdx.x;
    unsigned w = t >> 6, lane = t & 63u;

    // ---- Phase 1: per-wave ball-query scan ----
    const float* q = new_xyz + ((size_t)(b * M_ + m0 + w)) * 3;
    float qx = q[0], qy = q[1], qz = q[2];
    if (lane == 0) { s_q[w][0] = qx; s_q[w][1] = qy; s_q[w][2] = qz; }
    float qq = __fadd_rn(__fadd_rn(__fmul_rn(qx,qx), __fmul_rn(qy,qy)), __fmul_rn(qz,qz));
    const float* P = xyz + (size_t)b * N_ * 3;

    int done = 0;   // wave-uniform
    for (int nb = 0; nb < N_ && done < S_; nb += 256) {
        float px[4], py[4], pz[4];
        #pragma unroll
        for (int r = 0; r < 4; ++r) {      // all 12 loads issued up front
            int n = nb + r * 64 + (int)lane;
            px[r] = P[n*3+0]; py[r] = P[n*3+1]; pz[r] = P[n*3+2];
        }
        #pragma unroll
        for (int r = 0; r < 4; ++r) {
            float pp = __fadd_rn(__fadd_rn(__fmul_rn(px[r],px[r]), __fmul_rn(py[r],py[r])), __fmul_rn(pz[r],pz[r]));
            float dt = __fadd_rn(__fadd_rn(__fmul_rn(qz,pz[r]), __fmul_rn(qy,py[r])), __fmul_rn(qx,px[r]));
            float d  = __fsub_rn(__fadd_rn(qq, pp), __fmul_rn(2.0f, dt));
            unsigned long long mk = __ballot(d < 0.04f);   // strict <, f32(0.04)
            if ((mk >> lane) & 1ull) {
                int slot = done + __popcll(mk & ((1ull << lane) - 1ull));
                if (slot < S_) {
                    float4 v;
                    v.x = px[r]; v.y = py[r]; v.z = pz[r];
                    v.w = __int_as_float(nb + r * 64 + (int)lane);
                    s_sel[w][slot] = v;
                }
            }
            done += (int)__popcll(mk);
        }
    }
    if (lane == 0) s_done[w] = done;
    __syncthreads();

    // ---- Pad: slots [total,32) <- slot 0 if any valid, else {P[0..2], 0} ----
    if (t < 256) {
        int w2 = (int)(t >> 5), s = (int)(t & 31u);
        int dn = s_done[w2];
        int total = dn < S_ ? dn : S_;
        if (s >= total) {
            float4 v;
            if (dn > 0) v = s_sel[w2][0];   // slot 0 valid when dn>0
            else { v.x = P[0]; v.y = P[1]; v.z = P[2]; v.w = __int_as_float(0); }
            s_sel[w2][s] = v;
        }
    }
    __syncthreads();

    // ---- Phase 2a: coord channels 0..2 (3 waves x 8 m x 32 s = 1 KB runs) ----
    if (t < 192) {
        unsigned ch = t >> 6, l = t & 63u, qi = l >> 3, s4 = (l & 7u) * 4u;
        float qc = s_q[qi][ch];
        const float* sp = (const float*)&s_sel[qi][0];
        float4 v;
        v.x = __fsub_rn(sp[(s4 + 0) * 4 + ch], qc);
        v.y = __fsub_rn(sp[(s4 + 1) * 4 + ch], qc);
        v.z = __fsub_rn(sp[(s4 + 2) * 4 + ch], qc);
        v.w = __fsub_rn(sp[(s4 + 3) * 4 + ch], qc);
        size_t off = (((size_t)(b * C_OUT + ch)) * M_ + (m0 + qi)) * S_ + s4;
        store_nt(out + off, v);
    }

    // ---- Phase 2b: feature channels, 4 chunks of 32, pipelined gather ----
    unsigned p = t >> 1, h = t & 1u;           // pair per (q,s); 64 B halves
    unsigned qg = p >> 5, sg = p & 31u;
    float4 selv = s_sel[qg][sg];               // b128 read, conflict-free
    int n = __float_as_int(selv.w);
    const float* grow = g_ft + ((size_t)(b * N_ + n)) * C_FEAT + h * 16u;

    float4 r0 = ((const float4*)grow)[0];
    float4 r1 = ((const float4*)grow)[1];
    float4 r2 = ((const float4*)grow)[2];
    float4 r3 = ((const float4*)grow)[3];

    for (int k = 0; k < 4; ++k) {
        float4 n0v, n1v, n2v, n3v;
        if (k < 3) {                           // prefetch chunk k+1 (T14)
            const float4* src = (const float4*)(grow + (k + 1) * 32);
            n0v = src[0]; n1v = src[1]; n2v = src[2]; n3v = src[3];
        }
        unsigned cb = h * 16u;
        // Scatter: lanes 2p,2p+1 share a bank (2-way aliasing = free).
        sT[cb +  0][p] = r0.x; sT[cb +  1][p] = r0.y; sT[cb +  2][p] = r0.z; sT[cb +  3][p] = r0.w;
        sT[cb +  4][p] = r1.x; sT[cb +  5][p] = r1.y; sT[cb +  6][p] = r1.z; sT[cb +  7][p] = r1.w;
        sT[cb +  8][p] = r2.x; sT[cb +  9][p] = r2.y; sT[cb + 10][p] = r2.z; sT[cb + 11][p] = r2.w;
        sT[cb + 12][p] = r3.x; sT[cb + 13][p] = r3.y; sT[cb + 14][p] = r3.z; sT[cb + 15][p] = r3.w;
        lds_barrier();                         // scatter visible; VMEM stays in flight
        #pragma unroll
        for (int rep = 0; rep < 4; ++rep) {
            unsigned idx = rep * 512u + t;     // 32 ch x 64 float4
            unsigned chl = idx >> 6;           // wave-uniform channel
            unsigned l4  = (idx & 63u) * 4u;   // float offset in the 1 KB run
            float4 v = *((const float4*)&sT[chl][l4]);   // contiguous b128
            size_t off = (((size_t)(b * C_OUT + 3 + k * 32 + chl)) * M_ + m0) * S_ + l4;
            store_nt(out + off, v);
        }
        if (k < 3) lds_barrier();              // protect sT before next scatter
        r0 = n0v; r1 = n1v; r2 = n2v; r3 = n3v;
    }
}

extern "C" void kernel_launch(void* const* d_in, const int* in_sizes, int n_in,
                              void* d_out, int out_size, void* d_ws, size_t ws_size,
                              hipStream_t stream) {
    const float* xyz      = (const float*)d_in[0];  // (8,8192,3) f32
    const float* new_xyz  = (const float*)d_in[1];  // (8,2048,3) f32
    const float* features = (const float*)d_in[2];  // (8,128,8192) f32
    float* out = (float*)d_out;                     // (8,131,2048,32) f32

    // ATTRIBUTION ROUND 2: transpose launched TWICE (idempotent — pure function
    // of features). T_warm = dur_this_round - 323.3 µs. r8 gave F = 59.2 µs the
    // same way. Revert to single launch next round.
    transpose_kernel<<<dim3((N_ / 64) * (C_FEAT / 64) * B_), dim3(256), 0, stream>>>(features);
    transpose_kernel<<<dim3((N_ / 64) * (C_FEAT / 64) * B_), dim3(256), 0, stream>>>(features);
    fused_kernel<<<dim3(B_ * M_ / G_), dim3(512), 0, stream>>>(xyz, new_xyz, out);
}